// Round 3
// baseline (288.568 us; speedup 1.0000x reference)
//
#include <hip/hip_runtime.h>
#include <math.h>

// ---- problem constants ----
#define NUM_CLASSES 80
#define APS_ 3
#define BB 64
#define NN 32
constexpr int G0s = 52, G1s = 26, G2s = 13;
constexpr int R0 = BB * G0s * G0s * APS_;   // 519168 rows (scale 0)
constexpr int R1 = BB * G1s * G1s * APS_;   // 129792 rows (scale 1)
constexpr int R2 = BB * G2s * G2s * APS_;   //  32448 rows (scale 2)
constexpr int MROWS = R0 + R1 + R2;         // 681408 total rows
constexpr int CH = 5 + NUM_CLASSES;         // 85

// float4 counts per tensor (row counts all divisible by 4, so each tensor is a
// whole number of 85-float4 "groups" of 4 rows)
constexpr int F4_0 = R0 * CH / 4;           // 11,034,240
constexpr int F4_1 = R1 * CH / 4;           //  2,758,560
constexpr int F4_2 = R2 * CH / 4;           //    689,640
constexpr int F4_TOT = F4_0 + F4_1 + F4_2;  // 14,482,440

// grids
constexpr int OBJ_BLOCKS   = (BB * NN * 64) / 256;  // 512 blocks, 4 waves each
constexpr int SWEEP_BLOCKS = 2048;                  // 8 blocks/CU, grid-stride

// ws layout (floats), all plain-stored (fully overwritten every call -> no init):
// [0*OBJ_BLOCKS .. )           coord partial per obj-block
// [1*OBJ_BLOCKS .. )           conf-correction partial per obj-block
// [2*OBJ_BLOCKS .. )           class partial per obj-block
// [3*OBJ_BLOCKS .. )           n_obj count partial per obj-block
// [WS_SWEEP_OFF .. )           softplus(p4) partial per sweep-block
constexpr int WS_SWEEP_OFF = 4 * OBJ_BLOCKS;

__device__ __forceinline__ float softplusf(float x) {
    // == max(x,0) + log1p(exp(-|x|)) : exactly the bce(x,0) formula
    return fmaxf(x, 0.0f) + log1pf(expf(-fabsf(x)));
}

// key-only assignment (for dedup scans): scale, anchor-in-scale, cell iy/ix
__device__ __forceinline__ void box_key(const float* __restrict__ bboxes,
                                        const float* __restrict__ anchors,
                                        int b, int n,
                                        int& s, int& a, int& iy, int& ix) {
    const float* q = bboxes + (size_t)(b * NN + n) * 4;
    float x = q[0], y = q[1], w = q[2], h = q[3];
    float cx = x + w * 0.5f, cy = y + h * 0.5f;
    int best = 0;
    float bestd = 1e30f;
#pragma unroll
    for (int i = 0; i < 9; i++) {
        float d = fabsf(w - anchors[2 * i]) + fabsf(h - anchors[2 * i + 1]);
        if (d < bestd) { bestd = d; best = i; }   // strict < : first-min like argmin
    }
    s = best / 3;
    a = best - s * 3;
    int G = (s == 0) ? G0s : (s == 1) ? G1s : G2s;
    float cell = 1.0f / (float)G;                  // match ref: floor(cxy / cell)
    ix = (int)floorf(cx / cell);
    iy = (int)floorf(cy / cell);
}

// one wave (64 lanes) per box; per-block LDS reduce; ZERO atomics
__global__ void k_obj(const float* __restrict__ p0, const float* __restrict__ p1,
                      const float* __restrict__ p2,
                      const float* __restrict__ bboxes,
                      const int* __restrict__ labels,
                      const float* __restrict__ anchors,
                      float* __restrict__ ws) {
    int wid  = (blockIdx.x * blockDim.x + threadIdx.x) >> 6;  // box id (< BB*NN)
    int lane = threadIdx.x & 63;
    int wav  = threadIdx.x >> 6;                              // wave in block (0..3)
    int b = wid / NN, n = wid - b * NN;

    // every lane computes its own box's assignment (wave-uniform)
    int s, a, iy, ix;
    box_key(bboxes, anchors, b, n, s, a, iy, ix);

    // dedup: lane l probes box n+1+l of the same image; identical key means a
    // LATER box overwrites this target row (numpy last-write-wins) -> drop us.
    int n2 = n + 1 + lane;
    int match = 0;
    if (n2 < NN) {
        int s2, a2, iy2, ix2;
        box_key(bboxes, anchors, b, n2, s2, a2, iy2, ix2);
        match = (s2 == s) & (a2 == a) & (iy2 == iy) & (ix2 == ix);
    }
    bool superseded = __any(match);

    float coordp = 0.0f, confp = 0.0f, clsp = 0.0f;
    if (!superseded) {
        const float* q = bboxes + (size_t)(b * NN + n) * 4;
        float x = q[0], y = q[1], w = q[2], h = q[3];
        float cx = x + w * 0.5f, cy = y + h * 0.5f;
        int G = (s == 0) ? G0s : (s == 1) ? G1s : G2s;
        float cell = 1.0f / (float)G;
        float fx = (cx - (float)ix * cell) / cell + 1e-8f;
        float fy = (cy - (float)iy * cell) / cell + 1e-8f;
        float tx = -logf(1.0f / fx - 1.0f);
        float ty = -logf(1.0f / fy - 1.0f);
        int prior = s * 3 + a;
        float tw = logf(w / anchors[2 * prior]);
        float th = logf(h / anchors[2 * prior + 1]);
        int lab = labels[b * NN + n];

        const float* ps = (s == 0) ? p0 : (s == 1) ? p1 : p2;
        int row = ((b * G + iy) * G + ix) * APS_ + a;
        const float* prow = ps + (size_t)row * CH;

#pragma unroll
        for (int pass = 0; pass < 2; pass++) {
            int ch = lane + pass * 64;
            if (ch < CH) {
                float p = prow[ch];
                if (ch < 4) {
                    float t = (ch == 0) ? tx : (ch == 1) ? ty : (ch == 2) ? tw : th;
                    float d = p - t;
                    coordp += d * d;
                } else if (ch == 4) {
                    confp += -p;   // bce(x,1) - bce(x,0) = -x
                } else {
                    clsp += softplusf(p) - (((ch - 5) == lab) ? p : 0.0f);
                }
            }
        }
    }

#pragma unroll
    for (int o = 32; o > 0; o >>= 1) {
        coordp += __shfl_down(coordp, o);
        confp  += __shfl_down(confp,  o);
        clsp   += __shfl_down(clsp,   o);
    }

    __shared__ float sm[4][4];   // [wave][coord,conf,cls,cnt]
    if (lane == 0) {
        sm[wav][0] = coordp;
        sm[wav][1] = confp;
        sm[wav][2] = clsp;
        sm[wav][3] = superseded ? 0.0f : 1.0f;
    }
    __syncthreads();
    if (threadIdx.x == 0) {
        ws[0 * OBJ_BLOCKS + blockIdx.x] = sm[0][0] + sm[1][0] + sm[2][0] + sm[3][0];
        ws[1 * OBJ_BLOCKS + blockIdx.x] = sm[0][1] + sm[1][1] + sm[2][1] + sm[3][1];
        ws[2 * OBJ_BLOCKS + blockIdx.x] = sm[0][2] + sm[1][2] + sm[2][2] + sm[3][2];
        ws[3 * OBJ_BLOCKS + blockIdx.x] = sm[0][3] + sm[1][3] + sm[2][3] + sm[3][3];
    }
}

// bulk: coalesced float4 sweep of all three pred tensors; pick out channel-4
// dwords by structure (4 rows = 340 floats = 85 float4s; channel-4 dwords sit
// at group-local float4 indices {1,22,43,64}, component (jj-1)/21).
__global__ void k_sweep(const float4* __restrict__ p0, const float4* __restrict__ p1,
                        const float4* __restrict__ p2, float* __restrict__ ws) {
    const int stride = SWEEP_BLOCKS * 256;
    float acc = 0.0f;
    for (int j = blockIdx.x * 256 + threadIdx.x; j < F4_TOT; j += stride) {
        const float4* p;
        int lj;
        if (j < F4_0)             { p = p0; lj = j; }
        else if (j < F4_0 + F4_1) { p = p1; lj = j - F4_0; }
        else                      { p = p2; lj = j - F4_0 - F4_1; }
        float4 v = p[lj];
        int jj = lj % 85;          // group-local float4 index (compiler magic-mul)
        if (jj % 21 == 1) {        // jj in {1,22,43,64} for jj<85
            int comp = (jj - 1) / 21;
            float x = (comp == 0) ? v.x : (comp == 1) ? v.y : (comp == 2) ? v.z : v.w;
            acc += softplusf(x);
        }
    }
#pragma unroll
    for (int o = 32; o > 0; o >>= 1) acc += __shfl_down(acc, o);
    __shared__ float ls[4];
    if ((threadIdx.x & 63) == 0) ls[threadIdx.x >> 6] = acc;
    __syncthreads();
    if (threadIdx.x == 0)
        ws[WS_SWEEP_OFF + blockIdx.x] = (ls[0] + ls[1]) + (ls[2] + ls[3]);
}

// final: one block reduces all partials and writes the 4 outputs
__global__ void k_fin(const float* __restrict__ ws, float* __restrict__ out) {
    float coord_s = 0.0f, confc_s = 0.0f, cls_s = 0.0f, cnt_s = 0.0f, sp_s = 0.0f;
    for (int i = threadIdx.x; i < OBJ_BLOCKS; i += 256) {
        coord_s += ws[0 * OBJ_BLOCKS + i];
        confc_s += ws[1 * OBJ_BLOCKS + i];
        cls_s   += ws[2 * OBJ_BLOCKS + i];
        cnt_s   += ws[3 * OBJ_BLOCKS + i];
    }
    for (int i = threadIdx.x; i < SWEEP_BLOCKS; i += 256) {
        sp_s += ws[WS_SWEEP_OFF + i];
    }
#pragma unroll
    for (int o = 32; o > 0; o >>= 1) {
        coord_s += __shfl_down(coord_s, o);
        confc_s += __shfl_down(confc_s, o);
        cls_s   += __shfl_down(cls_s,   o);
        cnt_s   += __shfl_down(cnt_s,   o);
        sp_s    += __shfl_down(sp_s,    o);
    }
    __shared__ float ls[4][5];
    int lane = threadIdx.x & 63, wav = threadIdx.x >> 6;
    if (lane == 0) {
        ls[wav][0] = coord_s; ls[wav][1] = confc_s; ls[wav][2] = cls_s;
        ls[wav][3] = cnt_s;   ls[wav][4] = sp_s;
    }
    __syncthreads();
    if (threadIdx.x == 0) {
        float coord = ls[0][0] + ls[1][0] + ls[2][0] + ls[3][0];
        float confc = ls[0][1] + ls[1][1] + ls[2][1] + ls[3][1];
        float cls   = ls[0][2] + ls[1][2] + ls[2][2] + ls[3][2];
        float cnt   = ls[0][3] + ls[1][3] + ls[2][3] + ls[3][3];
        float sp    = ls[0][4] + ls[1][4] + ls[2][4] + ls[3][4];
        float n_obj = fmaxf(cnt, 1.0f);
        float coord_loss = 0.05f * coord / (n_obj * 4.0f);
        float conf_loss  = (sp + confc) / (float)MROWS;
        float class_loss = 0.5f * cls / (n_obj * (float)NUM_CLASSES);
        out[0] = coord_loss + conf_loss + class_loss;
        out[1] = coord_loss;
        out[2] = conf_loss;
        out[3] = class_loss;
    }
}

extern "C" void kernel_launch(void* const* d_in, const int* in_sizes, int n_in,
                              void* d_out, int out_size, void* d_ws, size_t ws_size,
                              hipStream_t stream) {
    const float* p0      = (const float*)d_in[0];
    const float* p1      = (const float*)d_in[1];
    const float* p2      = (const float*)d_in[2];
    const float* bboxes  = (const float*)d_in[3];
    const int*   labels  = (const int*)d_in[4];
    const float* anchors = (const float*)d_in[5];
    float* ws  = (float*)d_ws;
    float* out = (float*)d_out;

    k_obj<<<OBJ_BLOCKS, 256, 0, stream>>>(p0, p1, p2, bboxes, labels, anchors, ws);
    k_sweep<<<SWEEP_BLOCKS, 256, 0, stream>>>((const float4*)p0, (const float4*)p1,
                                              (const float4*)p2, ws);
    k_fin<<<1, 256, 0, stream>>>(ws, out);
}

// Round 4
// 259.096 us; speedup vs baseline: 1.1137x; 1.1137x over previous
//
#include <hip/hip_runtime.h>
#include <math.h>

// ---- problem constants ----
#define NUM_CLASSES 80
#define APS_ 3
#define BB 64
#define NN 32
constexpr int G0s = 52, G1s = 26, G2s = 13;
constexpr int R0 = BB * G0s * G0s * APS_;   // 519168 rows (scale 0)
constexpr int R1 = BB * G1s * G1s * APS_;   // 129792 rows (scale 1)
constexpr int R2 = BB * G2s * G2s * APS_;   //  32448 rows (scale 2)
constexpr int MROWS = R0 + R1 + R2;         // 681408 total rows
constexpr int CH = 5 + NUM_CLASSES;         // 85

// grids
constexpr int OBJ_BLOCKS  = (BB * NN) / 4;                 // 512 blocks' worth of boxes (4 waves/block)
constexpr int MAIN_THREADS = (MROWS + 3) / 4;              // 170352 (4 rows/thread gather)
constexpr int MAIN_BLOCKS  = (MAIN_THREADS + 255) / 256;   // 666  (>= OBJ_BLOCKS)

// ws layout (floats), all plain-stored (fully overwritten every call -> no init):
// [0*OBJ_BLOCKS .. )   coord partial per obj-block        (512)
// [1*OBJ_BLOCKS .. )   conf-correction partial            (512)
// [2*OBJ_BLOCKS .. )   class partial                      (512)
// [3*OBJ_BLOCKS .. )   n_obj count partial                (512)
// [WS_SP_OFF    .. )   softplus(p4) partial per main-block (666)
constexpr int WS_SP_OFF = 4 * OBJ_BLOCKS;

__device__ __forceinline__ float softplusf(float x) {
    // == max(x,0) + log1p(exp(-|x|)) : exactly the bce(x,0) formula
    return fmaxf(x, 0.0f) + log1pf(expf(-fabsf(x)));
}

// key-only assignment (for dedup scans): scale, anchor-in-scale, cell iy/ix
__device__ __forceinline__ void box_key(const float* __restrict__ bboxes,
                                        const float* __restrict__ anchors,
                                        int b, int n,
                                        int& s, int& a, int& iy, int& ix) {
    const float* q = bboxes + (size_t)(b * NN + n) * 4;
    float x = q[0], y = q[1], w = q[2], h = q[3];
    float cx = x + w * 0.5f, cy = y + h * 0.5f;
    int best = 0;
    float bestd = 1e30f;
#pragma unroll
    for (int i = 0; i < 9; i++) {
        float d = fabsf(w - anchors[2 * i]) + fabsf(h - anchors[2 * i + 1]);
        if (d < bestd) { bestd = d; best = i; }   // strict < : first-min like argmin
    }
    s = best / 3;
    a = best - s * 3;
    int G = (s == 0) ? G0s : (s == 1) ? G1s : G2s;
    float cell = 1.0f / (float)G;                  // match ref: floor(cxy / cell)
    ix = (int)floorf(cx / cell);
    iy = (int)floorf(cy / cell);
}

// Fused main kernel:
//  - ALL blocks: scattered channel-4 gather (4 rows/thread) -> softplus partial
//    (only ~43.6 MB of HBM lines touched vs 232 MB full sweep — measured faster)
//  - blocks < OBJ_BLOCKS: additionally one box per wave (obj terms), zero atomics
__global__ void k_main(const float* __restrict__ p0, const float* __restrict__ p1,
                       const float* __restrict__ p2,
                       const float* __restrict__ bboxes,
                       const int* __restrict__ labels,
                       const float* __restrict__ anchors,
                       float* __restrict__ ws) {
    int lane = threadIdx.x & 63;
    int wav  = threadIdx.x >> 6;

    // ---------------- bulk gather: softplus(pred[row][4]) ----------------
    int t  = blockIdx.x * 256 + threadIdx.x;
    int r0 = t * 4;
    float sv[4] = {0.0f, 0.0f, 0.0f, 0.0f};
#pragma unroll
    for (int k = 0; k < 4; k++) {
        int r = r0 + k;
        if (r < MROWS) {
            const float* p;
            int rr;
            if (r < R0)            { p = p0; rr = r; }
            else if (r < R0 + R1)  { p = p1; rr = r - R0; }
            else                   { p = p2; rr = r - R0 - R1; }
            sv[k] = softplusf(p[(size_t)rr * CH + 4]);
        }
    }
    float sp = (sv[0] + sv[1]) + (sv[2] + sv[3]);

    // ---------------- obj terms (first OBJ_BLOCKS blocks only) ----------------
    float coordp = 0.0f, confp = 0.0f, clsp = 0.0f;
    bool superseded = true;   // superseded==true contributes nothing / count 0
    if (blockIdx.x < OBJ_BLOCKS) {
        int wid = blockIdx.x * 4 + wav;           // box id, < BB*NN
        int b = wid / NN, n = wid - b * NN;

        int s, a, iy, ix;
        box_key(bboxes, anchors, b, n, s, a, iy, ix);

        // dedup: lane l probes box n+1+l of the same image; identical key means
        // a LATER box overwrites this target row (numpy last-write-wins).
        int n2 = n + 1 + lane;
        int match = 0;
        if (n2 < NN) {
            int s2, a2, iy2, ix2;
            box_key(bboxes, anchors, b, n2, s2, a2, iy2, ix2);
            match = (s2 == s) & (a2 == a) & (iy2 == iy) & (ix2 == ix);
        }
        superseded = __any(match);

        if (!superseded) {
            const float* q = bboxes + (size_t)(b * NN + n) * 4;
            float x = q[0], y = q[1], w = q[2], h = q[3];
            float cx = x + w * 0.5f, cy = y + h * 0.5f;
            int G = (s == 0) ? G0s : (s == 1) ? G1s : G2s;
            float cell = 1.0f / (float)G;
            float fx = (cx - (float)ix * cell) / cell + 1e-8f;
            float fy = (cy - (float)iy * cell) / cell + 1e-8f;
            float tx = -logf(1.0f / fx - 1.0f);
            float ty = -logf(1.0f / fy - 1.0f);
            int prior = s * 3 + a;
            float tw = logf(w / anchors[2 * prior]);
            float th = logf(h / anchors[2 * prior + 1]);
            int lab = labels[b * NN + n];

            const float* ps = (s == 0) ? p0 : (s == 1) ? p1 : p2;
            int row = ((b * G + iy) * G + ix) * APS_ + a;
            const float* prow = ps + (size_t)row * CH;

#pragma unroll
            for (int pass = 0; pass < 2; pass++) {
                int ch = lane + pass * 64;
                if (ch < CH) {
                    float p = prow[ch];
                    if (ch < 4) {
                        float tt = (ch == 0) ? tx : (ch == 1) ? ty : (ch == 2) ? tw : th;
                        float d = p - tt;
                        coordp += d * d;
                    } else if (ch == 4) {
                        confp += -p;   // bce(x,1) - bce(x,0) = -x
                    } else {
                        clsp += softplusf(p) - (((ch - 5) == lab) ? p : 0.0f);
                    }
                }
            }
        }
    }

    // ---------------- reductions ----------------
#pragma unroll
    for (int o = 32; o > 0; o >>= 1) {
        sp     += __shfl_down(sp,     o);
        coordp += __shfl_down(coordp, o);
        confp  += __shfl_down(confp,  o);
        clsp   += __shfl_down(clsp,   o);
    }

    __shared__ float sm[4][5];   // [wave][sp,coord,conf,cls,cnt]
    if (lane == 0) {
        sm[wav][0] = sp;
        sm[wav][1] = coordp;
        sm[wav][2] = confp;
        sm[wav][3] = clsp;
        sm[wav][4] = superseded ? 0.0f : 1.0f;
    }
    __syncthreads();
    if (threadIdx.x == 0) {
        ws[WS_SP_OFF + blockIdx.x] = sm[0][0] + sm[1][0] + sm[2][0] + sm[3][0];
        if (blockIdx.x < OBJ_BLOCKS) {
            ws[0 * OBJ_BLOCKS + blockIdx.x] = sm[0][1] + sm[1][1] + sm[2][1] + sm[3][1];
            ws[1 * OBJ_BLOCKS + blockIdx.x] = sm[0][2] + sm[1][2] + sm[2][2] + sm[3][2];
            ws[2 * OBJ_BLOCKS + blockIdx.x] = sm[0][3] + sm[1][3] + sm[2][3] + sm[3][3];
            ws[3 * OBJ_BLOCKS + blockIdx.x] = sm[0][4] + sm[1][4] + sm[2][4] + sm[3][4];
        }
    }
}

// final: one block reduces all partials and writes the 4 outputs
__global__ void k_fin(const float* __restrict__ ws, float* __restrict__ out) {
    float coord_s = 0.0f, confc_s = 0.0f, cls_s = 0.0f, cnt_s = 0.0f, sp_s = 0.0f;
    for (int i = threadIdx.x; i < OBJ_BLOCKS; i += 256) {
        coord_s += ws[0 * OBJ_BLOCKS + i];
        confc_s += ws[1 * OBJ_BLOCKS + i];
        cls_s   += ws[2 * OBJ_BLOCKS + i];
        cnt_s   += ws[3 * OBJ_BLOCKS + i];
    }
    for (int i = threadIdx.x; i < MAIN_BLOCKS; i += 256) {
        sp_s += ws[WS_SP_OFF + i];
    }
#pragma unroll
    for (int o = 32; o > 0; o >>= 1) {
        coord_s += __shfl_down(coord_s, o);
        confc_s += __shfl_down(confc_s, o);
        cls_s   += __shfl_down(cls_s,   o);
        cnt_s   += __shfl_down(cnt_s,   o);
        sp_s    += __shfl_down(sp_s,    o);
    }
    __shared__ float ls[4][5];
    int lane = threadIdx.x & 63, wav = threadIdx.x >> 6;
    if (lane == 0) {
        ls[wav][0] = coord_s; ls[wav][1] = confc_s; ls[wav][2] = cls_s;
        ls[wav][3] = cnt_s;   ls[wav][4] = sp_s;
    }
    __syncthreads();
    if (threadIdx.x == 0) {
        float coord = ls[0][0] + ls[1][0] + ls[2][0] + ls[3][0];
        float confc = ls[0][1] + ls[1][1] + ls[2][1] + ls[3][1];
        float cls   = ls[0][2] + ls[1][2] + ls[2][2] + ls[3][2];
        float cnt   = ls[0][3] + ls[1][3] + ls[2][3] + ls[3][3];
        float sp    = ls[0][4] + ls[1][4] + ls[2][4] + ls[3][4];
        float n_obj = fmaxf(cnt, 1.0f);
        float coord_loss = 0.05f * coord / (n_obj * 4.0f);
        float conf_loss  = (sp + confc) / (float)MROWS;
        float class_loss = 0.5f * cls / (n_obj * (float)NUM_CLASSES);
        out[0] = coord_loss + conf_loss + class_loss;
        out[1] = coord_loss;
        out[2] = conf_loss;
        out[3] = class_loss;
    }
}

extern "C" void kernel_launch(void* const* d_in, const int* in_sizes, int n_in,
                              void* d_out, int out_size, void* d_ws, size_t ws_size,
                              hipStream_t stream) {
    const float* p0      = (const float*)d_in[0];
    const float* p1      = (const float*)d_in[1];
    const float* p2      = (const float*)d_in[2];
    const float* bboxes  = (const float*)d_in[3];
    const int*   labels  = (const int*)d_in[4];
    const float* anchors = (const float*)d_in[5];
    float* ws  = (float*)d_ws;
    float* out = (float*)d_out;

    k_main<<<MAIN_BLOCKS, 256, 0, stream>>>(p0, p1, p2, bboxes, labels, anchors, ws);
    k_fin<<<1, 256, 0, stream>>>(ws, out);
}